// Round 1
// baseline (210.953 us; speedup 1.0000x reference)
//
#include <hip/hip_runtime.h>
#include <hip/hip_bf16.h>

typedef __bf16 bf16;
typedef __bf16 bf16x8 __attribute__((ext_vector_type(8)));
typedef __bf16 bf16x4 __attribute__((ext_vector_type(4)));
typedef float f32x4 __attribute__((ext_vector_type(4)));
typedef unsigned short u16;
typedef unsigned short u16x8 __attribute__((ext_vector_type(8)));

constexpr int kHW = 1024;   // 32*32
constexpr int kC  = 512;
constexpr int kB  = 16;
constexpr int kCPG = 16;    // channels per group (512/32)

__device__ inline float wave_sum(float v) {
#pragma unroll
    for (int o = 32; o; o >>= 1) v += __shfl_xor(v, o, 64);
    return v;
}
__device__ inline float wave_max(float v) {
#pragma unroll
    for (int o = 32; o; o >>= 1) v = fmaxf(v, __shfl_xor(v, o, 64));
    return v;
}

// ---------------- weight f32 -> bf16 ----------------
__global__ __launch_bounds__(256) void wconv_kernel(
    const float* __restrict__ wq, const float* __restrict__ wk,
    const float* __restrict__ wv, const float* __restrict__ wp,
    bf16* __restrict__ dst)
{
    int i = blockIdx.x * 256 + threadIdx.x;   // grid covers 262144
    dst[i]            = (bf16)wq[i];
    dst[262144 + i]   = (bf16)wk[i];
    dst[2*262144 + i] = (bf16)wv[i];
    dst[3*262144 + i] = (bf16)wp[i];
}

// ---------------- GroupNorm -> transposed bf16 [b][hw][c] ----------------
__global__ __launch_bounds__(256) void gn_kernel(
    const float* __restrict__ x, const float* __restrict__ scale,
    const float* __restrict__ bias, bf16* __restrict__ outT)
{
    int blk = blockIdx.x;            // b*32 + g
    int b = blk >> 5, g = blk & 31;
    int c0 = g * kCPG;
    const float* xg = x + ((size_t)b * kC + c0) * kHW;   // contiguous [16][1024]

    float s = 0.f, s2 = 0.f;
    const float4* xg4 = reinterpret_cast<const float4*>(xg);
#pragma unroll
    for (int i = 0; i < 16; ++i) {
        float4 v = xg4[threadIdx.x + i * 256];
        s  += v.x + v.y + v.z + v.w;
        s2 += v.x*v.x + v.y*v.y + v.z*v.z + v.w*v.w;
    }
    s = wave_sum(s); s2 = wave_sum(s2);
    __shared__ float red[8];
    int lane = threadIdx.x & 63, wid = threadIdx.x >> 6;
    if (!lane) { red[wid] = s; red[4 + wid] = s2; }
    __syncthreads();
    float ts = red[0] + red[1] + red[2] + red[3];
    float t2 = red[4] + red[5] + red[6] + red[7];
    float mean = ts * (1.f / 16384.f);
    float var  = t2 * (1.f / 16384.f) - mean * mean;
    float inv  = rsqrtf(var + 1e-6f);

    // pass 2: ci-fast so transposed writes are 32B-contiguous per 16 lanes
    int ci = threadIdx.x & 15;
    float a  = inv * scale[c0 + ci];
    float bb = bias[c0 + ci] - mean * a;
#pragma unroll
    for (int i = 0; i < 64; ++i) {
        int f = threadIdx.x + i * 256;
        int sp = f >> 4;
        float v = xg[ci * kHW + sp];          // L1/L2-hot from pass 1
        outT[((size_t)b * kHW + sp) * kC + c0 + ci] = (bf16)(v * a + bb);
    }
}

// ---------------- row softmax, f32 in, bf16 out (in-place, ld 2048) -------
__global__ __launch_bounds__(256) void softmax_kernel(float* __restrict__ S)
{
    size_t row = blockIdx.x;                    // b*1024 + i
    float* Srow = S + row * 1024;
    bf16*  Prow = reinterpret_cast<bf16*>(S) + row * 2048;
    int t = threadIdx.x;
    float4 v = reinterpret_cast<const float4*>(Srow)[t];
    float m = fmaxf(fmaxf(v.x, v.y), fmaxf(v.z, v.w));
    m = wave_max(m);
    __shared__ float redm[4], reds[4];
    int lane = t & 63, wid = t >> 6;
    if (!lane) redm[wid] = m;
    __syncthreads();
    m = fmaxf(fmaxf(redm[0], redm[1]), fmaxf(redm[2], redm[3]));
    float e0 = __expf(v.x - m), e1 = __expf(v.y - m);
    float e2 = __expf(v.z - m), e3 = __expf(v.w - m);
    float s = wave_sum(e0 + e1 + e2 + e3);
    if (!lane) reds[wid] = s;
    __syncthreads();
    s = reds[0] + reds[1] + reds[2] + reds[3];
    float r = 1.f / s;
    bf16x4 p = { (bf16)(e0 * r), (bf16)(e1 * r), (bf16)(e2 * r), (bf16)(e3 * r) };
    reinterpret_cast<bf16x4*>(Prow)[t] = p;     // row fully read before write
}

// ---------------- generic NT GEMM: C[M][N] = alpha*A[M][K]·B[N][K]^T ------
// BIAS: 0 none, 1 per-row(M), 2 per-col(N). RESID adds f32 residual.
template <int BIAS, bool RESID, typename OUT_T>
__global__ __launch_bounds__(256) void gemm_nt(
    const bf16* __restrict__ Ag, size_t sA, int lda,
    const bf16* __restrict__ Bg, size_t sB, int ldb,
    OUT_T* __restrict__ Cg, size_t sC, int ldc,
    const float* __restrict__ bias,
    const float* __restrict__ resid, size_t sR,
    int K, float alpha)
{
    __shared__ u16 As[128][72];   // BK=64, +8 pad: row stride 144B, <=2-way banks
    __shared__ u16 Bs[128][72];
    int bz = blockIdx.z;
    Ag += bz * sA; Bg += bz * sB; Cg += bz * sC;
    int brow = blockIdx.y * 128, bcol = blockIdx.x * 128;
    int t = threadIdx.x;
    int lane = t & 63, w = t >> 6;
    int wm = w >> 1, wn = w & 1;

    f32x4 acc[4][4] = {};
    const u16* Au = reinterpret_cast<const u16*>(Ag);
    const u16* Bu = reinterpret_cast<const u16*>(Bg);

    for (int k0 = 0; k0 < K; k0 += 64) {
#pragma unroll
        for (int p = 0; p < 4; ++p) {
            int idx = p * 256 + t;        // 1024 chunk positions
            int row = idx >> 3, ch = idx & 7;
            u16x8 va = *reinterpret_cast<const u16x8*>(Au + (size_t)(brow + row) * lda + k0 + ch * 8);
            *reinterpret_cast<u16x8*>(&As[row][ch * 8]) = va;
            u16x8 vb = *reinterpret_cast<const u16x8*>(Bu + (size_t)(bcol + row) * ldb + k0 + ch * 8);
            *reinterpret_cast<u16x8*>(&Bs[row][ch * 8]) = vb;
        }
        __syncthreads();
#pragma unroll
        for (int kk = 0; kk < 64; kk += 32) {
            bf16x8 a[4], bfr[4];
#pragma unroll
            for (int m = 0; m < 4; ++m)
                a[m] = *reinterpret_cast<const bf16x8*>(&As[wm*64 + m*16 + (lane & 15)][kk + (lane >> 4) * 8]);
#pragma unroll
            for (int n = 0; n < 4; ++n)
                bfr[n] = *reinterpret_cast<const bf16x8*>(&Bs[wn*64 + n*16 + (lane & 15)][kk + (lane >> 4) * 8]);
#pragma unroll
            for (int m = 0; m < 4; ++m)
#pragma unroll
                for (int n = 0; n < 4; ++n)
                    acc[m][n] = __builtin_amdgcn_mfma_f32_16x16x32_bf16(a[m], bfr[n], acc[m][n], 0, 0, 0);
        }
        __syncthreads();
    }

    int cr = lane >> 4, cc = lane & 15;
#pragma unroll
    for (int m = 0; m < 4; ++m) {
#pragma unroll
        for (int n = 0; n < 4; ++n) {
#pragma unroll
            for (int r = 0; r < 4; ++r) {
                int grow = brow + wm*64 + m*16 + cr*4 + r;
                int gcol = bcol + wn*64 + n*16 + cc;
                float vv = acc[m][n][r] * alpha;
                if (BIAS == 1) vv += bias[grow];
                if (BIAS == 2) vv += bias[gcol];
                if (RESID)     vv += resid[bz * sR + (size_t)grow * ldc + gcol];
                Cg[(size_t)grow * ldc + gcol] = (OUT_T)vv;
            }
        }
    }
}

extern "C" void kernel_launch(void* const* d_in, const int* in_sizes, int n_in,
                              void* d_out, int out_size, void* d_ws, size_t ws_size,
                              hipStream_t stream)
{
    const float* x   = (const float*)d_in[0];
    const float* y   = (const float*)d_in[1];
    const float* ns  = (const float*)d_in[2];
    const float* nb  = (const float*)d_in[3];
    const float* n1s = (const float*)d_in[4];
    const float* n1b = (const float*)d_in[5];
    const float* wq  = (const float*)d_in[6];
    const float* bq  = (const float*)d_in[7];
    const float* wk  = (const float*)d_in[8];
    const float* bk  = (const float*)d_in[9];
    const float* wv  = (const float*)d_in[10];
    const float* bv  = (const float*)d_in[11];
    const float* wp  = (const float*)d_in[12];
    const float* bp  = (const float*)d_in[13];
    float* out = (float*)d_out;

    char* ws = (char*)d_ws;
    bf16* wbf  = (bf16*)ws;                      // 4 x 512*512 bf16 = 2 MB
    bf16* wq_b = wbf;
    bf16* wk_b = wbf + 262144;
    bf16* wv_b = wbf + 2 * 262144;
    bf16* wp_b = wbf + 3 * 262144;
    bf16* hnT = (bf16*)(ws + 2097152);           // [b][hw][c] bf16
    bf16* ynT = hnT + 8388608;
    bf16* qT  = ynT + 8388608;                   // [b][hw][c]
    bf16* kT  = qT  + 8388608;                   // [b][hw][c]
    bf16* v   = kT  + 8388608;                   // [b][c][hw]
    bf16* aoT = v   + 8388608;                   // [b][hw][c]
    float* S  = (float*)(ws + 102760448);        // [b][1024][1024] f32; P aliased
    bf16*  P  = (bf16*)S;                        // ld = 2048 within S rows

    const size_t sBC = (size_t)kHW * kC;         // 524288 elements per batch
    const float scl = 0.044194173824159216f;     // 512^-0.5

    wconv_kernel<<<1024, 256, 0, stream>>>(wq, wk, wv, wp, wbf);
    gn_kernel<<<512, 256, 0, stream>>>(x, ns,  nb,  hnT);
    gn_kernel<<<512, 256, 0, stream>>>(y, n1s, n1b, ynT);

    // q_T[i][o] = yn_T[i][c] · wq[o][c] + bq[o]
    gemm_nt<2, false, bf16><<<dim3(4, 8, kB), 256, 0, stream>>>(
        ynT, sBC, 512, wq_b, 0, 512, qT, sBC, 512, bq, nullptr, 0, 512, 1.f);
    // k_T[j][o] = hn_T[j][c] · wk[o][c] + bk[o]
    gemm_nt<2, false, bf16><<<dim3(4, 8, kB), 256, 0, stream>>>(
        hnT, sBC, 512, wk_b, 0, 512, kT, sBC, 512, bk, nullptr, 0, 512, 1.f);
    // v[o][n] = wv[o][c] · hn_T[n][c] + bv[o]
    gemm_nt<1, false, bf16><<<dim3(8, 4, kB), 256, 0, stream>>>(
        wv_b, 0, 512, hnT, sBC, 512, v, sBC, 1024, bv, nullptr, 0, 512, 1.f);
    // S[i][j] = scl * q_T[i][c] · k_T[j][c]
    gemm_nt<0, false, float><<<dim3(8, 8, kB), 256, 0, stream>>>(
        qT, sBC, 512, kT, sBC, 512, S, (size_t)1048576, 1024,
        nullptr, nullptr, 0, 512, scl);
    softmax_kernel<<<16384, 256, 0, stream>>>(S);
    // ao_T[i][c] = P[i][j] · v[c][j]
    gemm_nt<0, false, bf16><<<dim3(4, 8, kB), 256, 0, stream>>>(
        P, (size_t)2097152, 2048, v, sBC, 1024, aoT, sBC, 512,
        nullptr, nullptr, 0, 1024, 1.f);
    // out[o][n] = wp[o][c] · ao_T[n][c] + bp[o] + x[o][n]
    gemm_nt<1, true, float><<<dim3(8, 4, kB), 256, 0, stream>>>(
        wp_b, 0, 512, aoT, sBC, 512, out, sBC, 1024, bp, x, sBC, 512, 1.f);
}